// Round 17
// baseline (216.635 us; speedup 1.0000x reference)
//
#include <hip/hip_runtime.h>
#include <hip/hip_bf16.h>

// SAGAN attention block: B=4, C=256, H=W=64 (N=4096).
// Round 17: algebraic restructure of the score path + merge fusion.
//  - S_ij = f_i.g_j  ==(softmax over i)==  x_i . u_j, u = (Wf^T Wg) x + Wf^T bg:
//    the bf-dependent terms are constant in i and cancel in softmax. So one
//    conv (u) replaces conv_fg, and attention's K-source is Xt itself (F gone).
//    M = Wf^T Wg computed in f32 (k_gemm_M, L2-resident), stored fp16.
//  - k_merge fused into k_conv_out (blend both OP splits in-register; -32MB).
//  - k_attn byte-identical to r16 (134.9us proven); OP in fresh space (XT live).

typedef short short8 __attribute__((ext_vector_type(8)));
typedef short short4v __attribute__((ext_vector_type(4)));
typedef float f32x4 __attribute__((ext_vector_type(4)));
typedef _Float16 f16x8 __attribute__((ext_vector_type(8)));
typedef unsigned short u16;
typedef unsigned int u32;

#define DEV static __device__ __forceinline__
#define MFMA16(a, b, c) __builtin_amdgcn_mfma_f32_16x16x32_f16(a, b, c, 0, 0, 0)

DEV u16 h16(float x) {
    union { _Float16 h; u16 u; } c;
    c.h = (_Float16)x;
    return c.u;
}
DEV f16x8 ldh8(const u16* p) { return *reinterpret_cast<const f16x8*>(p); }

DEV u32 cvtpk(float a, float b) {  // packed f16 (rtz): lo=a, hi=b
    u32 r;
    asm("v_cvt_pkrtz_f16_f32 %0, %1, %2" : "=v"(r) : "v"(a), "v"(b));
    return r;
}

// async global->LDS, 16B per lane; dst is wave-uniform base, HW adds lane*16
DEV void gload16(const void* g, void* l) {
    __builtin_amdgcn_global_load_lds(
        (const __attribute__((address_space(1))) unsigned int*)g,
        (__attribute__((address_space(3))) unsigned int*)l, 16, 0, 0);
}

// ---- workspace byte offsets ----
constexpr size_t OFF_WH = 0;          // 128K fp16
constexpr size_t OFF_WV = 131072;     // 128K fp16
constexpr size_t OFF_MB = 262144;     // 1K f32 (bias vector b = Wf^T bg)
constexpr size_t OFF_ML = 266240;     // 256K f32 pairs (2 splits x 16384 x {m,l})
constexpr size_t OFF_M  = 524288;     // 128K fp16 (M = Wf^T Wg)
constexpr size_t OFF_U  = 1310720;    // 8M fp16 [m][c]  (Q source: u)
constexpr size_t OFF_H  = OFF_U + 8388608;    // 8M fp16 [b][c][n] (V, keys permuted per 32-block)
constexpr size_t OFF_XT = OFF_H + 8388608;    // 8M fp16 [m][c]  (x; ALSO the attention K source)
constexpr size_t OFF_OP = OFF_XT + 8388608;   // 16M fp16 (2 splits) - fresh, XT stays live
// high-water mark = OFF_OP + 16777216 = 43,253,760 bytes

// ---------------- weight prep: Wh, Wv -> fp16 ----------------
__global__ __launch_bounds__(256) void k_prep_w(
    const float* __restrict__ Wh, const float* __restrict__ Wv, u16* WH, u16* WV) {
    int i = blockIdx.x * 256 + threadIdx.x;
    WH[i] = h16(Wh[i]);
    WV[i] = h16(Wv[i]);
}

// ---------------- M = Wf^T Wg (f32 accumulate, fp16 store); Mb = Wf^T bg ----------------
__global__ __launch_bounds__(256) void k_gemm_M(
    const float* __restrict__ Wf, const float* __restrict__ Wg,
    const float* __restrict__ bg, u16* __restrict__ M, float* __restrict__ Mb) {
    int c = blockIdx.x;       // row of M
    int t = threadIdx.x;      // col of M
    __shared__ float wf[256];
    wf[t] = Wf[(size_t)t * 256 + c];  // Wf[o=t][c]
    __syncthreads();
    float acc = 0.f;
    for (int o = 0; o < 256; ++o) acc += wf[o] * Wg[(size_t)o * 256 + t];
    M[(size_t)c * 256 + t] = h16(acc);
    if (t == 0) {
        float s = 0.f;
        for (int o = 0; o < 256; ++o) s += wf[o] * bg[o];
        Mb[c] = s;
    }
}

// ---------------- x transpose: x[b][c][n] f32 -> Xt[b][n][c] fp16 ----------------
__global__ __launch_bounds__(256) void k_prep_x(const float* __restrict__ x, u16* Xt) {
    __shared__ float lds[64][65];
    int bid = blockIdx.x;                 // 1024 blocks: b(4) x ctile(4) x ntile(64)
    int b = bid >> 8, rem = bid & 255, ct = rem >> 6, nt = rem & 63;
    int tid = threadIdx.x;
    int tx = tid & 63, ty = tid >> 6;
    const float* src = x + ((size_t)(b * 256 + ct * 64)) * 4096 + nt * 64;
#pragma unroll
    for (int k = 0; k < 16; ++k) {
        int cl = ty * 16 + k;
        lds[cl][tx] = src[(size_t)cl * 4096 + tx];
    }
    __syncthreads();
    int nl = tid >> 2, cg = tid & 3;
    short8 h0, h1;
#pragma unroll
    for (int j = 0; j < 8; ++j) h0[j] = (short)h16(lds[cg * 16 + j][nl]);
#pragma unroll
    for (int j = 8; j < 16; ++j) h1[j - 8] = (short)h16(lds[cg * 16 + j][nl]);
    size_t dst = ((size_t)(b * 4096 + nt * 64 + nl)) * 256 + ct * 64 + cg * 16;
    *reinterpret_cast<short8*>(Xt + dst) = h0;
    *reinterpret_cast<short8*>(Xt + dst + 8) = h1;
}

// ---------------- conv u: U[m][c] = sum_c' Xt[m][c'] M[c][c'] + Mb[c], fp16 out ----------------
__global__ __launch_bounds__(256) void k_conv_u(
    const u16* __restrict__ Xt, const u16* __restrict__ M,
    const float* __restrict__ Mb, u16* U) {
    int bidm = blockIdx.x & 255, bido = blockIdx.x >> 8;
    int w = threadIdx.x >> 6, lane = threadIdx.x & 63, r = lane & 15, g = lane >> 4;
    int m0 = bidm * 64 + w * 16, o0 = bido * 64;
    f32x4 ua[4];
#pragma unroll
    for (int i = 0; i < 4; ++i) ua[i] = {0.f, 0.f, 0.f, 0.f};
    const u16* ar = Xt + (size_t)(m0 + r) * 256;
#pragma unroll
    for (int ks = 0; ks < 8; ++ks) {
        int k0 = ks * 32 + 8 * g;
        f16x8 a = ldh8(ar + k0);
#pragma unroll
        for (int ot = 0; ot < 4; ++ot) {
            size_t wrow = (size_t)(o0 + ot * 16 + r) * 256 + k0;
            ua[ot] = MFMA16(a, ldh8(M + wrow), ua[ot]);
        }
    }
#pragma unroll
    for (int ot = 0; ot < 4; ++ot) {
#pragma unroll
        for (int q = 0; q < 4; ++q) {
            int row = m0 + 4 * g + q;
            int col = o0 + ot * 16 + r;
            U[(size_t)row * 256 + col] = h16(ua[ot][q] + Mb[col]);
        }
    }
}

// ---------------- conv h: fp16 MFMA, fp16 out, [b][c][n], keys permuted per 32-block ----------------
__global__ __launch_bounds__(256) void k_conv_h(
    const u16* __restrict__ WH, const u16* __restrict__ Xt,
    const float* __restrict__ bh, u16* Hb) {
    int bidn = blockIdx.x & 255, bido = blockIdx.x >> 8;
    int w = threadIdx.x >> 6, lane = threadIdx.x & 63, r = lane & 15, g = lane >> 4;
    int o0 = bido * 64 + w * 16, n0 = bidn * 64;
    f32x4 acc[4];
#pragma unroll
    for (int i = 0; i < 4; ++i) acc[i] = {0.f, 0.f, 0.f, 0.f};
    const u16* arow = WH + (size_t)(o0 + r) * 256;
#pragma unroll
    for (int ks = 0; ks < 8; ++ks) {
        int k0 = ks * 32 + 8 * g;
        f16x8 a = ldh8(arow + k0);
#pragma unroll
        for (int ntl = 0; ntl < 4; ++ntl) {
            f16x8 bb = ldh8(Xt + (size_t)(n0 + ntl * 16 + r) * 256 + k0);
            acc[ntl] = MFMA16(a, bb, acc[ntl]);
        }
    }
#pragma unroll
    for (int ntl = 0; ntl < 4; ++ntl) {
#pragma unroll
        for (int q = 0; q < 4; ++q) {
            int o = o0 + 4 * g + q;
            int nf = n0 + ntl * 16 + r;
            int bb = nf >> 12, n = nf & 4095;
            // permute key within its 32-block: slot kinv(k) holds key k, so the
            // attention PV B-fragment (slots 8g+j) is lane-local after swapped QK.
            int k5 = n & 31;
            int kp = (k5 < 16) ? (8 * (k5 >> 2) + (k5 & 3))
                               : (8 * ((k5 - 16) >> 2) + 4 + (k5 & 3));
            int np = (n & ~31) | kp;
            Hb[((size_t)(bb * 256 + o)) * 4096 + np] = h16(acc[ntl][q] + bh[o]);
        }
    }
}

// ---------------- flash attention: r16 verbatim (K=Xt, Q=U) ----------------
__global__ __launch_bounds__(256, 2) void k_attn(
    const u16* __restrict__ F, const u16* __restrict__ G,
    const u16* __restrict__ Hb, u16* __restrict__ OP, float* __restrict__ ML) {
    // K tile [32 keys][256 c] fp16, 16KB each, swizzle byte ^= (row&7)<<4.
    // V tile paired-row: byte(c,s) = (c>>1)*128 + ((s*2 + (c&1)*64) ^ (((c>>1)&7)<<4)),
    // slot s holds key kappa(s) (permutation baked into H by conv_h).
    __shared__ u16 Kd[2][8192];
    __shared__ u16 Vd[2][8192];

    int bid = blockIdx.x;            // 512 = 8 xcd * 64; 2 blocks/CU
    int xcd = bid & 7, idx = bid >> 3;
    int b = xcd >> 1, ks = xcd & 1;  // XCD carries (batch, key-half)
    int tid = threadIdx.x;
    int w = tid >> 6, lane = tid & 63, r = lane & 15, g = lane >> 4;
    int j0 = idx * 64 + w * 16;      // wave's 16 queries
    const float L2E = 1.4426950408889634f;

    // V lane-constant offset (ct part is ct*1024, an immediate)
    int vlc = (r >> 1) * 128 + (((16 * g) + (r & 1) * 64) ^ (((r >> 1) & 7) << 4));

    // Q as QK B-operand (col = query r): Qf[k] = Q[j0+r][k*32 + 8g .. +7]
    f16x8 Qf[8];
    {
        const u16* q = G + (size_t)(b * 4096 + j0 + r) * 256;
#pragma unroll
        for (int k = 0; k < 8; ++k) Qf[k] = ldh8(q + k * 32 + 8 * g);
    }
    // O[ct][q] = O[channel ct*16 + 4g + q][query j0 + r]
    f32x4 O[16];
#pragma unroll
    for (int i = 0; i < 16; ++i) O[i] = {0.f, 0.f, 0.f, 0.f};
    float m = -1e30f, l = 0.f;       // m wave-consistent per query; l LANE-PARTIAL

    const char* Fb  = (const char*)(F + (size_t)b * 4096 * 256);
    const char* Hbb = (const char*)(Hb + (size_t)b * 256 * 4096);

    // per-lane pre-swizzled stage source offsets (dest is linear)
    int ksrc[4], vsrc[4];
#pragma unroll
    for (int t = 0; t < 4; ++t) {
        int d = (w * 4 + t) * 1024 + lane * 16;
        int row = d >> 9, col = d & 511;
        ksrc[t] = row * 512 + (col ^ ((row & 7) << 4));
        int r128 = d >> 7, wn = d & 127;
        int wp = wn ^ ((r128 & 7) << 4);
        vsrc[t] = ((r128 * 2 + (wp >> 6)) << 13) + (wp & 63);
    }

#define STAGE(bufn, I0)                                                         \
    do {                                                                        \
        const char* kb_ = Fb + (size_t)(I0) * 512;                              \
        const char* vb_ = Hbb + (size_t)(I0) * 2;                               \
        char* kl = (char*)Kd[bufn];                                             \
        char* vl = (char*)Vd[bufn];                                             \
        _Pragma("unroll") for (int t = 0; t < 4; ++t)                           \
            gload16(kb_ + ksrc[t], kl + (w * 4 + t) * 1024);                    \
        _Pragma("unroll") for (int t = 0; t < 4; ++t)                           \
            gload16(vb_ + vsrc[t], vl + (w * 4 + t) * 1024);                    \
    } while (0)

    int i0beg = ks * 2048;
    STAGE(0, i0beg);   // prologue
    __syncthreads();   // drains vmcnt(0): tile 0 ready

    for (int it = 0; it < 64; ++it) {
        int cur = it & 1;
        if (it + 1 < 64) STAGE(cur ^ 1, i0beg + (it + 1) * 32);  // fly under compute

        const char* Kl = (const char*)Kd[cur];
        const char* Vb = (const char*)Vd[cur] + vlc;

        // ---- QK^T swapped: A = K (rows = keys), B = Q.
        f32x4 s0 = {0.f, 0.f, 0.f, 0.f};
        f32x4 s1 = {0.f, 0.f, 0.f, 0.f};
        __builtin_amdgcn_s_setprio(1);
        {
            const char* kr = Kl + r * 512;
            int sw = (r & 7) << 4;
#pragma unroll
            for (int k = 0; k < 8; ++k) {
                f16x8 ka = *reinterpret_cast<const f16x8*>(kr + ((k * 64 + 16 * g) ^ sw));
                s0 = MFMA16(ka, Qf[k], s0);
            }
        }
        {
            const char* kr = Kl + (16 + r) * 512;
            int sw = (r & 7) << 4;  // (16+r)&7 == r&7
#pragma unroll
            for (int k = 0; k < 8; ++k) {
                f16x8 ka = *reinterpret_cast<const f16x8*>(kr + ((k * 64 + 16 * g) ^ sw));
                s1 = MFMA16(ka, Qf[k], s1);
            }
        }
        __builtin_amdgcn_s_setprio(0);

        // ---- softmax: max reduced over g-lanes; l lane-partial ----
        float v = fmaxf(fmaxf(fmaxf(s0[0], s0[1]), fmaxf(s0[2], s0[3])),
                        fmaxf(fmaxf(s1[0], s1[1]), fmaxf(s1[2], s1[3])));
        v = fmaxf(v, __shfl_xor(v, 16));
        v = fmaxf(v, __shfl_xor(v, 32));
        float grow = v - m;
        if (__all(grow <= 8.0f)) {  // T13 defer-max: skip rescale
#pragma unroll
            for (int q = 0; q < 4; ++q) {
                s0[q] = exp2f((s0[q] - m) * L2E);
                s1[q] = exp2f((s1[q] - m) * L2E);
            }
            l += (s0[0] + s0[1] + s0[2] + s0[3]) + (s1[0] + s1[1] + s1[2] + s1[3]);
        } else {
            float mn = fmaxf(m, v);
            float corr = exp2f((m - mn) * L2E);
            m = mn;
#pragma unroll
            for (int q = 0; q < 4; ++q) {
                s0[q] = exp2f((s0[q] - m) * L2E);
                s1[q] = exp2f((s1[q] - m) * L2E);
            }
            l = l * corr + (s0[0] + s0[1] + s0[2] + s0[3]) + (s1[0] + s1[1] + s1[2] + s1[3]);
#pragma unroll
            for (int ct = 0; ct < 16; ++ct) O[ct] *= corr;  // whole lane = one query
        }

        // ---- P -> PV B-frag: LANE-LOCAL (V keys permuted by conv_h) ----
        union { u32 wd[4]; f16x8 fr; } pu;
        pu.wd[0] = cvtpk(s0[0], s0[1]);
        pu.wd[1] = cvtpk(s0[2], s0[3]);
        pu.wd[2] = cvtpk(s1[0], s1[1]);
        pu.wd[3] = cvtpk(s1[2], s1[3]);

        // ---- PV: O[c][j] += V[c][slot] * P[slot][j]; A = V (imm offsets) ----
        __builtin_amdgcn_s_setprio(1);
#pragma unroll
        for (int ct = 0; ct < 16; ++ct) {
            f16x8 vb = *reinterpret_cast<const f16x8*>(Vb + ct * 1024);
            O[ct] = MFMA16(vb, pu.fr, O[ct]);
        }
        __builtin_amdgcn_s_setprio(0);

        __syncthreads();  // drains vmcnt (next tile landed during compute)
    }
#undef STAGE

    // ---- finalize: reduce lane-partial l, normalize, store ----
    l += __shfl_xor(l, 16);
    l += __shfl_xor(l, 32);
    float inv = 1.f / l;
    size_t mrow = (size_t)ks * 16384 + b * 4096 + j0 + r;
#pragma unroll
    for (int ct = 0; ct < 16; ++ct) {
        short4v pk;
#pragma unroll
        for (int q = 0; q < 4; ++q) pk[q] = (short)h16(O[ct][q] * inv);
        *reinterpret_cast<short4v*>(OP + mrow * 256 + ct * 16 + 4 * g) = pk;
    }
    if (g == 0) {
        size_t mi = mrow * 2;
        ML[mi] = m;
        ML[mi + 1] = l;
    }
}

// ---------------- final conv, merge fused: blend both OP splits into B-frag ----------------
__global__ __launch_bounds__(256) void k_conv_out(
    const u16* __restrict__ WV, const u16* __restrict__ OP,
    const float* __restrict__ ML, const float* __restrict__ bv,
    float* __restrict__ out) {
    int bidn = blockIdx.x & 255, bido = blockIdx.x >> 8;
    int w = threadIdx.x >> 6, lane = threadIdx.x & 63, r = lane & 15, g = lane >> 4;
    int o0 = bido * 64 + w * 16, n0 = bidn * 64;
    const float L2E = 1.4426950408889634f;
    // per-lane merge weights for the 4 B-rows this lane supplies
    float wl0[4], wl1[4];
    int nfs[4];
#pragma unroll
    for (int ntl = 0; ntl < 4; ++ntl) {
        int nf = n0 + ntl * 16 + r;
        nfs[ntl] = nf;
        float m0_ = ML[(size_t)nf * 2], l0_ = ML[(size_t)nf * 2 + 1];
        float m1_ = ML[((size_t)16384 + nf) * 2], l1_ = ML[((size_t)16384 + nf) * 2 + 1];
        float M_ = fmaxf(m0_, m1_);
        float a0 = exp2f((m0_ - M_) * L2E) * l0_;
        float a1 = exp2f((m1_ - M_) * L2E) * l1_;
        float inv = 1.f / (a0 + a1);
        wl0[ntl] = a0 * inv;
        wl1[ntl] = a1 * inv;
    }
    f32x4 acc[4];
#pragma unroll
    for (int i = 0; i < 4; ++i) acc[i] = {0.f, 0.f, 0.f, 0.f};
    const u16* arow = WV + (size_t)(o0 + r) * 256;
#pragma unroll
    for (int ks = 0; ks < 8; ++ks) {
        int k0 = ks * 32 + 8 * g;
        f16x8 a = ldh8(arow + k0);
#pragma unroll
        for (int ntl = 0; ntl < 4; ++ntl) {
            f16x8 v0 = ldh8(OP + (size_t)nfs[ntl] * 256 + k0);
            f16x8 v1 = ldh8(OP + ((size_t)16384 + nfs[ntl]) * 256 + k0);
            union { u32 wd[4]; f16x8 fr; } bb;
#pragma unroll
            for (int j = 0; j < 4; ++j) {
                float e0 = wl0[ntl] * (float)v0[2 * j] + wl1[ntl] * (float)v1[2 * j];
                float e1 = wl0[ntl] * (float)v0[2 * j + 1] + wl1[ntl] * (float)v1[2 * j + 1];
                bb.wd[j] = cvtpk(e0, e1);
            }
            acc[ntl] = MFMA16(a, bb.fr, acc[ntl]);
        }
    }
#pragma unroll
    for (int ntl = 0; ntl < 4; ++ntl) {
#pragma unroll
        for (int q = 0; q < 4; ++q) {
            int o = o0 + 4 * g + q;
            int nf = nfs[ntl] - r + r;  // = n0 + ntl*16 + r
            int bb2 = nf >> 12, n = nf & 4095;
            out[((size_t)(bb2 * 256 + o)) * 4096 + n] = acc[ntl][q] + bv[o];
        }
    }
}

extern "C" void kernel_launch(void* const* d_in, const int* in_sizes, int n_in,
                              void* d_out, int out_size, void* d_ws, size_t ws_size,
                              hipStream_t stream) {
    const float* x  = (const float*)d_in[0];
    const float* Wf = (const float*)d_in[1];
    const float* bf = (const float*)d_in[2];  // cancels in softmax (const in i)
    const float* Wg = (const float*)d_in[3];
    const float* bg = (const float*)d_in[4];
    const float* Wh = (const float*)d_in[5];
    const float* bh = (const float*)d_in[6];
    const float* Wv = (const float*)d_in[7];
    const float* bv = (const float*)d_in[8];
    float* out = (float*)d_out;
    char* ws = (char*)d_ws;
    (void)bf;

    u16* WH = (u16*)(ws + OFF_WH);
    u16* WV = (u16*)(ws + OFF_WV);
    float* MB = (float*)(ws + OFF_MB);
    float* ML = (float*)(ws + OFF_ML);
    u16* M  = (u16*)(ws + OFF_M);
    u16* U  = (u16*)(ws + OFF_U);
    u16* H  = (u16*)(ws + OFF_H);
    u16* XT = (u16*)(ws + OFF_XT);
    u16* OP = (u16*)(ws + OFF_OP);

    k_prep_w<<<256, 256, 0, stream>>>(Wh, Wv, WH, WV);
    k_gemm_M<<<256, 256, 0, stream>>>(Wf, Wg, bg, M, MB);
    k_prep_x<<<1024, 256, 0, stream>>>(x, XT);
    k_conv_u<<<1024, 256, 0, stream>>>(XT, M, MB, U);
    k_conv_h<<<1024, 256, 0, stream>>>(WH, XT, bh, H);
    k_attn<<<512, 256, 0, stream>>>(XT, U, H, OP, ML);  // K = Xt, Q = U
    k_conv_out<<<1024, 256, 0, stream>>>(WV, OP, ML, bv, out);
}

// Round 18
// 211.366 us; speedup vs baseline: 1.0249x; 1.0249x over previous
//
#include <hip/hip_runtime.h>
#include <hip/hip_bf16.h>

// SAGAN attention block: B=4, C=256, H=W=64 (N=4096).
// Round 18 = r17 + critical-path fix in k_attn's softmax: the 2 shfl_xor
// (~120cy LDS latency each, serial) were only needed to form a per-query
// consistent max, but the defer-max COMMON path's condition
// "all queries' tile-max <= m+8" is exactly __all(v_lane - m <= 8) -- a
// wave-wide AND needs no shuffle. The shuffles move into the rare rescale
// branch. Common-path iter loses ~240 serial cycles. Rest identical to r17.

typedef short short8 __attribute__((ext_vector_type(8)));
typedef short short4v __attribute__((ext_vector_type(4)));
typedef float f32x4 __attribute__((ext_vector_type(4)));
typedef _Float16 f16x8 __attribute__((ext_vector_type(8)));
typedef unsigned short u16;
typedef unsigned int u32;

#define DEV static __device__ __forceinline__
#define MFMA16(a, b, c) __builtin_amdgcn_mfma_f32_16x16x32_f16(a, b, c, 0, 0, 0)

DEV u16 h16(float x) {
    union { _Float16 h; u16 u; } c;
    c.h = (_Float16)x;
    return c.u;
}
DEV f16x8 ldh8(const u16* p) { return *reinterpret_cast<const f16x8*>(p); }

DEV u32 cvtpk(float a, float b) {  // packed f16 (rtz): lo=a, hi=b
    u32 r;
    asm("v_cvt_pkrtz_f16_f32 %0, %1, %2" : "=v"(r) : "v"(a), "v"(b));
    return r;
}

// async global->LDS, 16B per lane; dst is wave-uniform base, HW adds lane*16
DEV void gload16(const void* g, void* l) {
    __builtin_amdgcn_global_load_lds(
        (const __attribute__((address_space(1))) unsigned int*)g,
        (__attribute__((address_space(3))) unsigned int*)l, 16, 0, 0);
}

// ---- workspace byte offsets ----
constexpr size_t OFF_WH = 0;          // 128K fp16
constexpr size_t OFF_WV = 131072;     // 128K fp16
constexpr size_t OFF_MB = 262144;     // 1K f32 (bias vector b = Wf^T bg)
constexpr size_t OFF_ML = 266240;     // 256K f32 pairs (2 splits x 16384 x {m,l})
constexpr size_t OFF_M  = 524288;     // 128K fp16 (M = Wf^T Wg)
constexpr size_t OFF_U  = 1310720;    // 8M fp16 [m][c]  (Q source: u)
constexpr size_t OFF_H  = OFF_U + 8388608;    // 8M fp16 [b][c][n] (V, keys permuted per 32-block)
constexpr size_t OFF_XT = OFF_H + 8388608;    // 8M fp16 [m][c]  (x; ALSO the attention K source)
constexpr size_t OFF_OP = OFF_XT + 8388608;   // 16M fp16 (2 splits) - fresh, XT stays live
// high-water mark = OFF_OP + 16777216 = 43,253,760 bytes

// ---------------- weight prep: Wh, Wv -> fp16 ----------------
__global__ __launch_bounds__(256) void k_prep_w(
    const float* __restrict__ Wh, const float* __restrict__ Wv, u16* WH, u16* WV) {
    int i = blockIdx.x * 256 + threadIdx.x;
    WH[i] = h16(Wh[i]);
    WV[i] = h16(Wv[i]);
}

// ---------------- M = Wf^T Wg (f32 accumulate, fp16 store); Mb = Wf^T bg ----------------
__global__ __launch_bounds__(256) void k_gemm_M(
    const float* __restrict__ Wf, const float* __restrict__ Wg,
    const float* __restrict__ bg, u16* __restrict__ M, float* __restrict__ Mb) {
    int c = blockIdx.x;       // row of M
    int t = threadIdx.x;      // col of M
    __shared__ float wf[256];
    wf[t] = Wf[(size_t)t * 256 + c];  // Wf[o=t][c]
    __syncthreads();
    float acc = 0.f;
    for (int o = 0; o < 256; ++o) acc += wf[o] * Wg[(size_t)o * 256 + t];
    M[(size_t)c * 256 + t] = h16(acc);
    if (t == 0) {
        float s = 0.f;
        for (int o = 0; o < 256; ++o) s += wf[o] * bg[o];
        Mb[c] = s;
    }
}

// ---------------- x transpose: x[b][c][n] f32 -> Xt[b][n][c] fp16 ----------------
__global__ __launch_bounds__(256) void k_prep_x(const float* __restrict__ x, u16* Xt) {
    __shared__ float lds[64][65];
    int bid = blockIdx.x;                 // 1024 blocks: b(4) x ctile(4) x ntile(64)
    int b = bid >> 8, rem = bid & 255, ct = rem >> 6, nt = rem & 63;
    int tid = threadIdx.x;
    int tx = tid & 63, ty = tid >> 6;
    const float* src = x + ((size_t)(b * 256 + ct * 64)) * 4096 + nt * 64;
#pragma unroll
    for (int k = 0; k < 16; ++k) {
        int cl = ty * 16 + k;
        lds[cl][tx] = src[(size_t)cl * 4096 + tx];
    }
    __syncthreads();
    int nl = tid >> 2, cg = tid & 3;
    short8 h0, h1;
#pragma unroll
    for (int j = 0; j < 8; ++j) h0[j] = (short)h16(lds[cg * 16 + j][nl]);
#pragma unroll
    for (int j = 8; j < 16; ++j) h1[j - 8] = (short)h16(lds[cg * 16 + j][nl]);
    size_t dst = ((size_t)(b * 4096 + nt * 64 + nl)) * 256 + ct * 64 + cg * 16;
    *reinterpret_cast<short8*>(Xt + dst) = h0;
    *reinterpret_cast<short8*>(Xt + dst + 8) = h1;
}

// ---------------- conv u: U[m][c] = sum_c' Xt[m][c'] M[c][c'] + Mb[c], fp16 out ----------------
__global__ __launch_bounds__(256) void k_conv_u(
    const u16* __restrict__ Xt, const u16* __restrict__ M,
    const float* __restrict__ Mb, u16* U) {
    int bidm = blockIdx.x & 255, bido = blockIdx.x >> 8;
    int w = threadIdx.x >> 6, lane = threadIdx.x & 63, r = lane & 15, g = lane >> 4;
    int m0 = bidm * 64 + w * 16, o0 = bido * 64;
    f32x4 ua[4];
#pragma unroll
    for (int i = 0; i < 4; ++i) ua[i] = {0.f, 0.f, 0.f, 0.f};
    const u16* ar = Xt + (size_t)(m0 + r) * 256;
#pragma unroll
    for (int ks = 0; ks < 8; ++ks) {
        int k0 = ks * 32 + 8 * g;
        f16x8 a = ldh8(ar + k0);
#pragma unroll
        for (int ot = 0; ot < 4; ++ot) {
            size_t wrow = (size_t)(o0 + ot * 16 + r) * 256 + k0;
            ua[ot] = MFMA16(a, ldh8(M + wrow), ua[ot]);
        }
    }
#pragma unroll
    for (int ot = 0; ot < 4; ++ot) {
#pragma unroll
        for (int q = 0; q < 4; ++q) {
            int row = m0 + 4 * g + q;
            int col = o0 + ot * 16 + r;
            U[(size_t)row * 256 + col] = h16(ua[ot][q] + Mb[col]);
        }
    }
}

// ---------------- conv h: fp16 MFMA, fp16 out, [b][c][n], keys permuted per 32-block ----------------
__global__ __launch_bounds__(256) void k_conv_h(
    const u16* __restrict__ WH, const u16* __restrict__ Xt,
    const float* __restrict__ bh, u16* Hb) {
    int bidn = blockIdx.x & 255, bido = blockIdx.x >> 8;
    int w = threadIdx.x >> 6, lane = threadIdx.x & 63, r = lane & 15, g = lane >> 4;
    int o0 = bido * 64 + w * 16, n0 = bidn * 64;
    f32x4 acc[4];
#pragma unroll
    for (int i = 0; i < 4; ++i) acc[i] = {0.f, 0.f, 0.f, 0.f};
    const u16* arow = WH + (size_t)(o0 + r) * 256;
#pragma unroll
    for (int ks = 0; ks < 8; ++ks) {
        int k0 = ks * 32 + 8 * g;
        f16x8 a = ldh8(arow + k0);
#pragma unroll
        for (int ntl = 0; ntl < 4; ++ntl) {
            f16x8 bb = ldh8(Xt + (size_t)(n0 + ntl * 16 + r) * 256 + k0);
            acc[ntl] = MFMA16(a, bb, acc[ntl]);
        }
    }
#pragma unroll
    for (int ntl = 0; ntl < 4; ++ntl) {
#pragma unroll
        for (int q = 0; q < 4; ++q) {
            int o = o0 + 4 * g + q;
            int nf = n0 + ntl * 16 + r;
            int bb = nf >> 12, n = nf & 4095;
            // permute key within its 32-block: slot kinv(k) holds key k, so the
            // attention PV B-fragment (slots 8g+j) is lane-local after swapped QK.
            int k5 = n & 31;
            int kp = (k5 < 16) ? (8 * (k5 >> 2) + (k5 & 3))
                               : (8 * ((k5 - 16) >> 2) + 4 + (k5 & 3));
            int np = (n & ~31) | kp;
            Hb[((size_t)(bb * 256 + o)) * 4096 + np] = h16(acc[ntl][q] + bh[o]);
        }
    }
}

// ---------------- flash attention: swapped-QK 16x16, shuffle-free common path ----------------
__global__ __launch_bounds__(256, 2) void k_attn(
    const u16* __restrict__ F, const u16* __restrict__ G,
    const u16* __restrict__ Hb, u16* __restrict__ OP, float* __restrict__ ML) {
    // K tile [32 keys][256 c] fp16, 16KB each, swizzle byte ^= (row&7)<<4.
    // V tile paired-row: byte(c,s) = (c>>1)*128 + ((s*2 + (c&1)*64) ^ (((c>>1)&7)<<4)),
    // slot s holds key kappa(s) (permutation baked into H by conv_h).
    __shared__ u16 Kd[2][8192];
    __shared__ u16 Vd[2][8192];

    int bid = blockIdx.x;            // 512 = 8 xcd * 64; 2 blocks/CU
    int xcd = bid & 7, idx = bid >> 3;
    int b = xcd >> 1, ks = xcd & 1;  // XCD carries (batch, key-half)
    int tid = threadIdx.x;
    int w = tid >> 6, lane = tid & 63, r = lane & 15, g = lane >> 4;
    int j0 = idx * 64 + w * 16;      // wave's 16 queries
    const float L2E = 1.4426950408889634f;

    // V lane-constant offset (ct part is ct*1024, an immediate)
    int vlc = (r >> 1) * 128 + (((16 * g) + (r & 1) * 64) ^ (((r >> 1) & 7) << 4));

    // Q as QK B-operand (col = query r): Qf[k] = Q[j0+r][k*32 + 8g .. +7]
    f16x8 Qf[8];
    {
        const u16* q = G + (size_t)(b * 4096 + j0 + r) * 256;
#pragma unroll
        for (int k = 0; k < 8; ++k) Qf[k] = ldh8(q + k * 32 + 8 * g);
    }
    // O[ct][q] = O[channel ct*16 + 4g + q][query j0 + r]
    f32x4 O[16];
#pragma unroll
    for (int i = 0; i < 16; ++i) O[i] = {0.f, 0.f, 0.f, 0.f};
    float m = -1e30f, l = 0.f;       // m wave-consistent per query; l LANE-PARTIAL

    const char* Fb  = (const char*)(F + (size_t)b * 4096 * 256);
    const char* Hbb = (const char*)(Hb + (size_t)b * 256 * 4096);

    // per-lane pre-swizzled stage source offsets (dest is linear)
    int ksrc[4], vsrc[4];
#pragma unroll
    for (int t = 0; t < 4; ++t) {
        int d = (w * 4 + t) * 1024 + lane * 16;
        int row = d >> 9, col = d & 511;
        ksrc[t] = row * 512 + (col ^ ((row & 7) << 4));
        int r128 = d >> 7, wn = d & 127;
        int wp = wn ^ ((r128 & 7) << 4);
        vsrc[t] = ((r128 * 2 + (wp >> 6)) << 13) + (wp & 63);
    }

#define STAGE(bufn, I0)                                                         \
    do {                                                                        \
        const char* kb_ = Fb + (size_t)(I0) * 512;                              \
        const char* vb_ = Hbb + (size_t)(I0) * 2;                               \
        char* kl = (char*)Kd[bufn];                                             \
        char* vl = (char*)Vd[bufn];                                             \
        _Pragma("unroll") for (int t = 0; t < 4; ++t)                           \
            gload16(kb_ + ksrc[t], kl + (w * 4 + t) * 1024);                    \
        _Pragma("unroll") for (int t = 0; t < 4; ++t)                           \
            gload16(vb_ + vsrc[t], vl + (w * 4 + t) * 1024);                    \
    } while (0)

    int i0beg = ks * 2048;
    STAGE(0, i0beg);   // prologue
    __syncthreads();   // drains vmcnt(0): tile 0 ready

    for (int it = 0; it < 64; ++it) {
        int cur = it & 1;
        if (it + 1 < 64) STAGE(cur ^ 1, i0beg + (it + 1) * 32);  // fly under compute

        const char* Kl = (const char*)Kd[cur];
        const char* Vb = (const char*)Vd[cur] + vlc;

        // ---- QK^T swapped: A = K (rows = keys), B = Q.
        f32x4 s0 = {0.f, 0.f, 0.f, 0.f};
        f32x4 s1 = {0.f, 0.f, 0.f, 0.f};
        __builtin_amdgcn_s_setprio(1);
        {
            const char* kr = Kl + r * 512;
            int sw = (r & 7) << 4;
#pragma unroll
            for (int k = 0; k < 8; ++k) {
                f16x8 ka = *reinterpret_cast<const f16x8*>(kr + ((k * 64 + 16 * g) ^ sw));
                s0 = MFMA16(ka, Qf[k], s0);
            }
        }
        {
            const char* kr = Kl + (16 + r) * 512;
            int sw = (r & 7) << 4;  // (16+r)&7 == r&7
#pragma unroll
            for (int k = 0; k < 8; ++k) {
                f16x8 ka = *reinterpret_cast<const f16x8*>(kr + ((k * 64 + 16 * g) ^ sw));
                s1 = MFMA16(ka, Qf[k], s1);
            }
        }
        __builtin_amdgcn_s_setprio(0);

        // ---- softmax: SHUFFLE-FREE common path. v = this lane's 8-score max;
        // "all queries' tile-max <= m+8" == __all(v - m <= 8) (wave-wide AND;
        // the 4 g-lanes of each query jointly cover its 32 keys). ----
        float v = fmaxf(fmaxf(fmaxf(s0[0], s0[1]), fmaxf(s0[2], s0[3])),
                        fmaxf(fmaxf(s1[0], s1[1]), fmaxf(s1[2], s1[3])));
        if (!__all(v - m <= 8.0f)) {  // rare: full per-query max + rescale
            v = fmaxf(v, __shfl_xor(v, 16));
            v = fmaxf(v, __shfl_xor(v, 32));
            float mn = fmaxf(m, v);
            float corr = exp2f((m - mn) * L2E);
            m = mn;
            l *= corr;
#pragma unroll
            for (int ct = 0; ct < 16; ++ct) O[ct] *= corr;  // whole lane = one query
        }
#pragma unroll
        for (int q = 0; q < 4; ++q) {
            s0[q] = exp2f((s0[q] - m) * L2E);
            s1[q] = exp2f((s1[q] - m) * L2E);
        }
        l += (s0[0] + s0[1] + s0[2] + s0[3]) + (s1[0] + s1[1] + s1[2] + s1[3]);

        // ---- P -> PV B-frag: LANE-LOCAL (V keys permuted by conv_h) ----
        union { u32 wd[4]; f16x8 fr; } pu;
        pu.wd[0] = cvtpk(s0[0], s0[1]);
        pu.wd[1] = cvtpk(s0[2], s0[3]);
        pu.wd[2] = cvtpk(s1[0], s1[1]);
        pu.wd[3] = cvtpk(s1[2], s1[3]);

        // ---- PV: O[c][j] += V[c][slot] * P[slot][j]; A = V (imm offsets) ----
        __builtin_amdgcn_s_setprio(1);
#pragma unroll
        for (int ct = 0; ct < 16; ++ct) {
            f16x8 vb = *reinterpret_cast<const f16x8*>(Vb + ct * 1024);
            O[ct] = MFMA16(vb, pu.fr, O[ct]);
        }
        __builtin_amdgcn_s_setprio(0);

        __syncthreads();  // drains vmcnt (next tile landed during compute)
    }
#undef STAGE

    // ---- finalize: reduce lane-partial l, normalize, store ----
    l += __shfl_xor(l, 16);
    l += __shfl_xor(l, 32);
    float inv = 1.f / l;
    size_t mrow = (size_t)ks * 16384 + b * 4096 + j0 + r;
#pragma unroll
    for (int ct = 0; ct < 16; ++ct) {
        short4v pk;
#pragma unroll
        for (int q = 0; q < 4; ++q) pk[q] = (short)h16(O[ct][q] * inv);
        *reinterpret_cast<short4v*>(OP + mrow * 256 + ct * 16 + 4 * g) = pk;
    }
    if (g == 0) {
        size_t mi = mrow * 2;
        ML[mi] = m;
        ML[mi + 1] = l;
    }
}

// ---------------- final conv, merge fused: blend both OP splits into B-frag ----------------
__global__ __launch_bounds__(256) void k_conv_out(
    const u16* __restrict__ WV, const u16* __restrict__ OP,
    const float* __restrict__ ML, const float* __restrict__ bv,
    float* __restrict__ out) {
    int bidn = blockIdx.x & 255, bido = blockIdx.x >> 8;
    int w = threadIdx.x >> 6, lane = threadIdx.x & 63, r = lane & 15, g = lane >> 4;
    int o0 = bido * 64 + w * 16, n0 = bidn * 64;
    const float L2E = 1.4426950408889634f;
    float wl0[4], wl1[4];
    int nfs[4];
#pragma unroll
    for (int ntl = 0; ntl < 4; ++ntl) {
        int nf = n0 + ntl * 16 + r;
        nfs[ntl] = nf;
        float m0_ = ML[(size_t)nf * 2], l0_ = ML[(size_t)nf * 2 + 1];
        float m1_ = ML[((size_t)16384 + nf) * 2], l1_ = ML[((size_t)16384 + nf) * 2 + 1];
        float M_ = fmaxf(m0_, m1_);
        float a0 = exp2f((m0_ - M_) * L2E) * l0_;
        float a1 = exp2f((m1_ - M_) * L2E) * l1_;
        float inv = 1.f / (a0 + a1);
        wl0[ntl] = a0 * inv;
        wl1[ntl] = a1 * inv;
    }
    f32x4 acc[4];
#pragma unroll
    for (int i = 0; i < 4; ++i) acc[i] = {0.f, 0.f, 0.f, 0.f};
    const u16* arow = WV + (size_t)(o0 + r) * 256;
#pragma unroll
    for (int ks = 0; ks < 8; ++ks) {
        int k0 = ks * 32 + 8 * g;
        f16x8 a = ldh8(arow + k0);
#pragma unroll
        for (int ntl = 0; ntl < 4; ++ntl) {
            f16x8 v0 = ldh8(OP + (size_t)nfs[ntl] * 256 + k0);
            f16x8 v1 = ldh8(OP + ((size_t)16384 + nfs[ntl]) * 256 + k0);
            union { u32 wd[4]; f16x8 fr; } bb;
#pragma unroll
            for (int j = 0; j < 4; ++j) {
                float e0 = wl0[ntl] * (float)v0[2 * j] + wl1[ntl] * (float)v1[2 * j];
                float e1 = wl0[ntl] * (float)v0[2 * j + 1] + wl1[ntl] * (float)v1[2 * j + 1];
                bb.wd[j] = cvtpk(e0, e1);
            }
            acc[ntl] = MFMA16(a, bb.fr, acc[ntl]);
        }
    }
#pragma unroll
    for (int ntl = 0; ntl < 4; ++ntl) {
#pragma unroll
        for (int q = 0; q < 4; ++q) {
            int o = o0 + 4 * g + q;
            int nf = nfs[ntl];
            int bb2 = nf >> 12, n = nf & 4095;
            out[((size_t)(bb2 * 256 + o)) * 4096 + n] = acc[ntl][q] + bv[o];
        }
    }
}

extern "C" void kernel_launch(void* const* d_in, const int* in_sizes, int n_in,
                              void* d_out, int out_size, void* d_ws, size_t ws_size,
                              hipStream_t stream) {
    const float* x  = (const float*)d_in[0];
    const float* Wf = (const float*)d_in[1];
    const float* bf = (const float*)d_in[2];  // cancels in softmax (const in i)
    const float* Wg = (const float*)d_in[3];
    const float* bg = (const float*)d_in[4];
    const float* Wh = (const float*)d_in[5];
    const float* bh = (const float*)d_in[6];
    const float* Wv = (const float*)d_in[7];
    const float* bv = (const float*)d_in[8];
    float* out = (float*)d_out;
    char* ws = (char*)d_ws;
    (void)bf;

    u16* WH = (u16*)(ws + OFF_WH);
    u16* WV = (u16*)(ws + OFF_WV);
    float* MB = (float*)(ws + OFF_MB);
    float* ML = (float*)(ws + OFF_ML);
    u16* M  = (u16*)(ws + OFF_M);
    u16* U  = (u16*)(ws + OFF_U);
    u16* H  = (u16*)(ws + OFF_H);
    u16* XT = (u16*)(ws + OFF_XT);
    u16* OP = (u16*)(ws + OFF_OP);

    k_prep_w<<<256, 256, 0, stream>>>(Wh, Wv, WH, WV);
    k_gemm_M<<<256, 256, 0, stream>>>(Wf, Wg, bg, M, MB);
    k_prep_x<<<1024, 256, 0, stream>>>(x, XT);
    k_conv_u<<<1024, 256, 0, stream>>>(XT, M, MB, U);
    k_conv_h<<<1024, 256, 0, stream>>>(WH, XT, bh, H);
    k_attn<<<512, 256, 0, stream>>>(XT, U, H, OP, ML);  // K = Xt, Q = U
    k_conv_out<<<1024, 256, 0, stream>>>(WV, OP, ML, bv, out);
}

// Round 19
// 204.703 us; speedup vs baseline: 1.0583x; 1.0326x over previous
//
#include <hip/hip_runtime.h>
#include <hip/hip_bf16.h>

// SAGAN attention block: B=4, C=256, H=W=64 (N=4096).
// Round 19 = r18 with the prep pipeline fused (7 kernels -> 4):
//  - k_prep = prep_x + conv_u + conv_h in one kernel: transpose x into an LDS
//    tile [64][264] fp16 (row-padded, conflict-free b128 reads), write XT once,
//    then compute U and H from LDS (A-frags loaded once, reused for both).
//    Kills 64MB of XT re-reads + 2 launches. H via swapped operands (A=Xt).
//  - k_gemm_M also converts Wh/Wv rows (prep_w folded in).
//  - k_attn / k_conv_out byte-identical to r18 (attn 128us proven).

typedef short short8 __attribute__((ext_vector_type(8)));
typedef short short4v __attribute__((ext_vector_type(4)));
typedef float f32x4 __attribute__((ext_vector_type(4)));
typedef _Float16 f16x8 __attribute__((ext_vector_type(8)));
typedef unsigned short u16;
typedef unsigned int u32;

#define DEV static __device__ __forceinline__
#define MFMA16(a, b, c) __builtin_amdgcn_mfma_f32_16x16x32_f16(a, b, c, 0, 0, 0)

DEV u16 h16(float x) {
    union { _Float16 h; u16 u; } c;
    c.h = (_Float16)x;
    return c.u;
}
DEV f16x8 ldh8(const u16* p) { return *reinterpret_cast<const f16x8*>(p); }

DEV u32 cvtpk(float a, float b) {  // packed f16 (rtz): lo=a, hi=b
    u32 r;
    asm("v_cvt_pkrtz_f16_f32 %0, %1, %2" : "=v"(r) : "v"(a), "v"(b));
    return r;
}

// async global->LDS, 16B per lane; dst is wave-uniform base, HW adds lane*16
DEV void gload16(const void* g, void* l) {
    __builtin_amdgcn_global_load_lds(
        (const __attribute__((address_space(1))) unsigned int*)g,
        (__attribute__((address_space(3))) unsigned int*)l, 16, 0, 0);
}

// ---- workspace byte offsets ----
constexpr size_t OFF_WH = 0;          // 128K fp16
constexpr size_t OFF_WV = 131072;     // 128K fp16
constexpr size_t OFF_MB = 262144;     // 1K f32 (bias vector b = Wf^T bg)
constexpr size_t OFF_ML = 266240;     // 256K f32 pairs (2 splits x 16384 x {m,l})
constexpr size_t OFF_M  = 524288;     // 128K fp16 (M = Wf^T Wg)
constexpr size_t OFF_U  = 1310720;    // 8M fp16 [m][c]  (Q source: u)
constexpr size_t OFF_H  = OFF_U + 8388608;    // 8M fp16 [b][c][n] (V, keys permuted per 32-block)
constexpr size_t OFF_XT = OFF_H + 8388608;    // 8M fp16 [m][c]  (x; ALSO the attention K source)
constexpr size_t OFF_OP = OFF_XT + 8388608;   // 16M fp16 (2 splits)
// high-water mark = OFF_OP + 16777216 = 43,253,760 bytes

// ---------------- M = Wf^T Wg (+Mb); also converts Wh,Wv rows to fp16 ----------------
__global__ __launch_bounds__(256) void k_gemm_M(
    const float* __restrict__ Wf, const float* __restrict__ Wg,
    const float* __restrict__ bg, const float* __restrict__ Wh,
    const float* __restrict__ Wv,
    u16* __restrict__ M, float* __restrict__ Mb, u16* WH, u16* WV) {
    int c = blockIdx.x;       // row of M (and of Wh/Wv to convert)
    int t = threadIdx.x;      // col
    size_t rowi = (size_t)c * 256 + t;
    WH[rowi] = h16(Wh[rowi]);
    WV[rowi] = h16(Wv[rowi]);
    __shared__ float wf[256];
    wf[t] = Wf[(size_t)t * 256 + c];  // Wf[o=t][c]
    __syncthreads();
    float acc = 0.f;
    for (int o = 0; o < 256; ++o) acc += wf[o] * Wg[(size_t)o * 256 + t];
    M[rowi] = h16(acc);
    if (t == 0) {
        float s = 0.f;
        for (int o = 0; o < 256; ++o) s += wf[o] * bg[o];
        Mb[c] = s;
    }
}

// ---------------- fused prep: x -> Xt (global+LDS), then U and H from LDS ----------------
__global__ __launch_bounds__(256) void k_prep(
    const float* __restrict__ x, const u16* __restrict__ M,
    const float* __restrict__ Mb, const u16* __restrict__ WH,
    const float* __restrict__ bh,
    u16* __restrict__ Xt, u16* __restrict__ U, u16* __restrict__ Hb) {
    __shared__ float tbuf[64][65];   // transpose scratch (f32)
    __shared__ u16 xt[64][264];      // row-padded fp16 tile (stride 528B)

    int bid = blockIdx.x;            // 256 blocks: 64-row stripes of m
    int m0 = bid * 64;
    int b = m0 >> 12, n0 = m0 & 4095;
    int tid = threadIdx.x;
    int tx = tid & 63, ty = tid >> 6;
    int nl = tid >> 2, cg = tid & 3;

    // ---- phase 1: transpose x[b][c][n0..63] -> xt LDS tile + XT global ----
    for (int ct4 = 0; ct4 < 4; ++ct4) {
        const float* src = x + ((size_t)(b * 256 + ct4 * 64)) * 4096 + n0;
#pragma unroll
        for (int k = 0; k < 16; ++k) {
            int cl = ty * 16 + k;
            tbuf[cl][tx] = src[(size_t)cl * 4096 + tx];
        }
        __syncthreads();
        short8 h0, h1;
#pragma unroll
        for (int j = 0; j < 8; ++j) h0[j] = (short)h16(tbuf[cg * 16 + j][nl]);
#pragma unroll
        for (int j = 8; j < 16; ++j) h1[j - 8] = (short)h16(tbuf[cg * 16 + j][nl]);
        int colbase = ct4 * 64 + cg * 16;
        *reinterpret_cast<short8*>(&xt[nl][colbase]) = h0;
        *reinterpret_cast<short8*>(&xt[nl][colbase + 8]) = h1;
        size_t dst = ((size_t)(m0 + nl)) * 256 + colbase;
        *reinterpret_cast<short8*>(Xt + dst) = h0;
        *reinterpret_cast<short8*>(Xt + dst + 8) = h1;
        __syncthreads();
    }

    // ---- phase 2: U[m][o] and H[o][n] from the LDS tile ----
    int w = tid >> 6, lane = tid & 63, r = lane & 15, g = lane >> 4;
    // A-frags: rows = this wave's 16 n-rows (lane r), k-chunk by lane g
    f16x8 A[8];
#pragma unroll
    for (int ks = 0; ks < 8; ++ks)
        A[ks] = *reinterpret_cast<const f16x8*>(&xt[w * 16 + r][ks * 32 + 8 * g]);

#pragma unroll 4
    for (int ot = 0; ot < 16; ++ot) {
        f32x4 au = {0.f, 0.f, 0.f, 0.f};
        f32x4 ah = {0.f, 0.f, 0.f, 0.f};
        const u16* mrow = M + (size_t)(ot * 16 + r) * 256;
        const u16* hrow = WH + (size_t)(ot * 16 + r) * 256;
#pragma unroll
        for (int ks = 0; ks < 8; ++ks) {
            int k0 = ks * 32 + 8 * g;
            au = MFMA16(A[ks], ldh8(mrow + k0), au);
            ah = MFMA16(A[ks], ldh8(hrow + k0), ah);
        }
        // D rows = n-local (4g+q), cols = o (r)
        int o = ot * 16 + r;
        float mb = Mb[o];
        float bhv = bh[o];
#pragma unroll
        for (int q = 0; q < 4; ++q) {
            int rloc = w * 16 + 4 * g + q;
            U[(size_t)(m0 + rloc) * 256 + o] = h16(au[q] + mb);
            int n = n0 + rloc;
            int k5 = n & 31;
            int kp = (k5 < 16) ? (8 * (k5 >> 2) + (k5 & 3))
                               : (8 * ((k5 - 16) >> 2) + 4 + (k5 & 3));
            int np = (n & ~31) | kp;
            Hb[((size_t)(b * 256 + o)) * 4096 + np] = h16(ah[q] + bhv);
        }
    }
}

// ---------------- flash attention: r18 verbatim (K=Xt, Q=U) ----------------
__global__ __launch_bounds__(256, 2) void k_attn(
    const u16* __restrict__ F, const u16* __restrict__ G,
    const u16* __restrict__ Hb, u16* __restrict__ OP, float* __restrict__ ML) {
    __shared__ u16 Kd[2][8192];
    __shared__ u16 Vd[2][8192];

    int bid = blockIdx.x;            // 512 = 8 xcd * 64; 2 blocks/CU
    int xcd = bid & 7, idx = bid >> 3;
    int b = xcd >> 1, ks = xcd & 1;  // XCD carries (batch, key-half)
    int tid = threadIdx.x;
    int w = tid >> 6, lane = tid & 63, r = lane & 15, g = lane >> 4;
    int j0 = idx * 64 + w * 16;      // wave's 16 queries
    const float L2E = 1.4426950408889634f;

    int vlc = (r >> 1) * 128 + (((16 * g) + (r & 1) * 64) ^ (((r >> 1) & 7) << 4));

    f16x8 Qf[8];
    {
        const u16* q = G + (size_t)(b * 4096 + j0 + r) * 256;
#pragma unroll
        for (int k = 0; k < 8; ++k) Qf[k] = ldh8(q + k * 32 + 8 * g);
    }
    f32x4 O[16];
#pragma unroll
    for (int i = 0; i < 16; ++i) O[i] = {0.f, 0.f, 0.f, 0.f};
    float m = -1e30f, l = 0.f;

    const char* Fb  = (const char*)(F + (size_t)b * 4096 * 256);
    const char* Hbb = (const char*)(Hb + (size_t)b * 256 * 4096);

    int ksrc[4], vsrc[4];
#pragma unroll
    for (int t = 0; t < 4; ++t) {
        int d = (w * 4 + t) * 1024 + lane * 16;
        int row = d >> 9, col = d & 511;
        ksrc[t] = row * 512 + (col ^ ((row & 7) << 4));
        int r128 = d >> 7, wn = d & 127;
        int wp = wn ^ ((r128 & 7) << 4);
        vsrc[t] = ((r128 * 2 + (wp >> 6)) << 13) + (wp & 63);
    }

#define STAGE(bufn, I0)                                                         \
    do {                                                                        \
        const char* kb_ = Fb + (size_t)(I0) * 512;                              \
        const char* vb_ = Hbb + (size_t)(I0) * 2;                               \
        char* kl = (char*)Kd[bufn];                                             \
        char* vl = (char*)Vd[bufn];                                             \
        _Pragma("unroll") for (int t = 0; t < 4; ++t)                           \
            gload16(kb_ + ksrc[t], kl + (w * 4 + t) * 1024);                    \
        _Pragma("unroll") for (int t = 0; t < 4; ++t)                           \
            gload16(vb_ + vsrc[t], vl + (w * 4 + t) * 1024);                    \
    } while (0)

    int i0beg = ks * 2048;
    STAGE(0, i0beg);   // prologue
    __syncthreads();   // drains vmcnt(0): tile 0 ready

    for (int it = 0; it < 64; ++it) {
        int cur = it & 1;
        if (it + 1 < 64) STAGE(cur ^ 1, i0beg + (it + 1) * 32);

        const char* Kl = (const char*)Kd[cur];
        const char* Vb = (const char*)Vd[cur] + vlc;

        f32x4 s0 = {0.f, 0.f, 0.f, 0.f};
        f32x4 s1 = {0.f, 0.f, 0.f, 0.f};
        __builtin_amdgcn_s_setprio(1);
        {
            const char* kr = Kl + r * 512;
            int sw = (r & 7) << 4;
#pragma unroll
            for (int k = 0; k < 8; ++k) {
                f16x8 ka = *reinterpret_cast<const f16x8*>(kr + ((k * 64 + 16 * g) ^ sw));
                s0 = MFMA16(ka, Qf[k], s0);
            }
        }
        {
            const char* kr = Kl + (16 + r) * 512;
            int sw = (r & 7) << 4;
#pragma unroll
            for (int k = 0; k < 8; ++k) {
                f16x8 ka = *reinterpret_cast<const f16x8*>(kr + ((k * 64 + 16 * g) ^ sw));
                s1 = MFMA16(ka, Qf[k], s1);
            }
        }
        __builtin_amdgcn_s_setprio(0);

        float v = fmaxf(fmaxf(fmaxf(s0[0], s0[1]), fmaxf(s0[2], s0[3])),
                        fmaxf(fmaxf(s1[0], s1[1]), fmaxf(s1[2], s1[3])));
        if (!__all(v - m <= 8.0f)) {  // rare: full per-query max + rescale
            v = fmaxf(v, __shfl_xor(v, 16));
            v = fmaxf(v, __shfl_xor(v, 32));
            float mn = fmaxf(m, v);
            float corr = exp2f((m - mn) * L2E);
            m = mn;
            l *= corr;
#pragma unroll
            for (int ct = 0; ct < 16; ++ct) O[ct] *= corr;
        }
#pragma unroll
        for (int q = 0; q < 4; ++q) {
            s0[q] = exp2f((s0[q] - m) * L2E);
            s1[q] = exp2f((s1[q] - m) * L2E);
        }
        l += (s0[0] + s0[1] + s0[2] + s0[3]) + (s1[0] + s1[1] + s1[2] + s1[3]);

        union { u32 wd[4]; f16x8 fr; } pu;
        pu.wd[0] = cvtpk(s0[0], s0[1]);
        pu.wd[1] = cvtpk(s0[2], s0[3]);
        pu.wd[2] = cvtpk(s1[0], s1[1]);
        pu.wd[3] = cvtpk(s1[2], s1[3]);

        __builtin_amdgcn_s_setprio(1);
#pragma unroll
        for (int ct = 0; ct < 16; ++ct) {
            f16x8 vb = *reinterpret_cast<const f16x8*>(Vb + ct * 1024);
            O[ct] = MFMA16(vb, pu.fr, O[ct]);
        }
        __builtin_amdgcn_s_setprio(0);

        __syncthreads();
    }
#undef STAGE

    l += __shfl_xor(l, 16);
    l += __shfl_xor(l, 32);
    float inv = 1.f / l;
    size_t mrow = (size_t)ks * 16384 + b * 4096 + j0 + r;
#pragma unroll
    for (int ct = 0; ct < 16; ++ct) {
        short4v pk;
#pragma unroll
        for (int q = 0; q < 4; ++q) pk[q] = (short)h16(O[ct][q] * inv);
        *reinterpret_cast<short4v*>(OP + mrow * 256 + ct * 16 + 4 * g) = pk;
    }
    if (g == 0) {
        size_t mi = mrow * 2;
        ML[mi] = m;
        ML[mi + 1] = l;
    }
}

// ---------------- final conv, merge fused: blend both OP splits into B-frag ----------------
__global__ __launch_bounds__(256) void k_conv_out(
    const u16* __restrict__ WV, const u16* __restrict__ OP,
    const float* __restrict__ ML, const float* __restrict__ bv,
    float* __restrict__ out) {
    int bidn = blockIdx.x & 255, bido = blockIdx.x >> 8;
    int w = threadIdx.x >> 6, lane = threadIdx.x & 63, r = lane & 15, g = lane >> 4;
    int o0 = bido * 64 + w * 16, n0 = bidn * 64;
    const float L2E = 1.4426950408889634f;
    float wl0[4], wl1[4];
    int nfs[4];
#pragma unroll
    for (int ntl = 0; ntl < 4; ++ntl) {
        int nf = n0 + ntl * 16 + r;
        nfs[ntl] = nf;
        float m0_ = ML[(size_t)nf * 2], l0_ = ML[(size_t)nf * 2 + 1];
        float m1_ = ML[((size_t)16384 + nf) * 2], l1_ = ML[((size_t)16384 + nf) * 2 + 1];
        float M_ = fmaxf(m0_, m1_);
        float a0 = exp2f((m0_ - M_) * L2E) * l0_;
        float a1 = exp2f((m1_ - M_) * L2E) * l1_;
        float inv = 1.f / (a0 + a1);
        wl0[ntl] = a0 * inv;
        wl1[ntl] = a1 * inv;
    }
    f32x4 acc[4];
#pragma unroll
    for (int i = 0; i < 4; ++i) acc[i] = {0.f, 0.f, 0.f, 0.f};
    const u16* arow = WV + (size_t)(o0 + r) * 256;
#pragma unroll
    for (int ks = 0; ks < 8; ++ks) {
        int k0 = ks * 32 + 8 * g;
        f16x8 a = ldh8(arow + k0);
#pragma unroll
        for (int ntl = 0; ntl < 4; ++ntl) {
            f16x8 v0 = ldh8(OP + (size_t)nfs[ntl] * 256 + k0);
            f16x8 v1 = ldh8(OP + ((size_t)16384 + nfs[ntl]) * 256 + k0);
            union { u32 wd[4]; f16x8 fr; } bb;
#pragma unroll
            for (int j = 0; j < 4; ++j) {
                float e0 = wl0[ntl] * (float)v0[2 * j] + wl1[ntl] * (float)v1[2 * j];
                float e1 = wl0[ntl] * (float)v0[2 * j + 1] + wl1[ntl] * (float)v1[2 * j + 1];
                bb.wd[j] = cvtpk(e0, e1);
            }
            acc[ntl] = MFMA16(a, bb.fr, acc[ntl]);
        }
    }
#pragma unroll
    for (int ntl = 0; ntl < 4; ++ntl) {
#pragma unroll
        for (int q = 0; q < 4; ++q) {
            int o = o0 + 4 * g + q;
            int nf = nfs[ntl];
            int bb2 = nf >> 12, n = nf & 4095;
            out[((size_t)(bb2 * 256 + o)) * 4096 + n] = acc[ntl][q] + bv[o];
        }
    }
}

extern "C" void kernel_launch(void* const* d_in, const int* in_sizes, int n_in,
                              void* d_out, int out_size, void* d_ws, size_t ws_size,
                              hipStream_t stream) {
    const float* x  = (const float*)d_in[0];
    const float* Wf = (const float*)d_in[1];
    const float* bf = (const float*)d_in[2];  // cancels in softmax (const in i)
    const float* Wg = (const float*)d_in[3];
    const float* bg = (const float*)d_in[4];
    const float* Wh = (const float*)d_in[5];
    const float* bh = (const float*)d_in[6];
    const float* Wv = (const float*)d_in[7];
    const float* bv = (const float*)d_in[8];
    float* out = (float*)d_out;
    char* ws = (char*)d_ws;
    (void)bf;

    u16* WH = (u16*)(ws + OFF_WH);
    u16* WV = (u16*)(ws + OFF_WV);
    float* MB = (float*)(ws + OFF_MB);
    float* ML = (float*)(ws + OFF_ML);
    u16* M  = (u16*)(ws + OFF_M);
    u16* U  = (u16*)(ws + OFF_U);
    u16* H  = (u16*)(ws + OFF_H);
    u16* XT = (u16*)(ws + OFF_XT);
    u16* OP = (u16*)(ws + OFF_OP);

    k_gemm_M<<<256, 256, 0, stream>>>(Wf, Wg, bg, Wh, Wv, M, MB, WH, WV);
    k_prep<<<256, 256, 0, stream>>>(x, M, MB, WH, bh, XT, U, H);
    k_attn<<<512, 256, 0, stream>>>(XT, U, H, OP, ML);  // K = Xt, Q = U
    k_conv_out<<<1024, 256, 0, stream>>>(WV, OP, ML, bv, out);
}